// Round 3
// baseline (680.708 us; speedup 1.0000x reference)
//
#include <hip/hip_runtime.h>

// Problem constants
#define B_    2
#define T_    2048
#define HID_  2048
#define NH_   32
#define NKV_  8
#define HD_   64
#define STEPS_ 2
#define SCALE_ 0.125f
// SCALE * log2(e): scores kept in exp2 domain throughout (folded into q at RoPE)
#define CSC_  0.18033688011112042f

typedef float   f32x4  __attribute__((ext_vector_type(4)));
typedef __bf16  bf16x8 __attribute__((ext_vector_type(8)));
typedef unsigned short u16x8 __attribute__((ext_vector_type(8)));

__device__ __forceinline__ unsigned short f2bf(float f) {
  unsigned int u = __builtin_bit_cast(unsigned int, f);
  u = (u + 0x7fffu + ((u >> 16) & 1u)) >> 16;
  return (unsigned short)u;
}
__device__ __forceinline__ float bf2f(unsigned short h) {
  unsigned int u = ((unsigned int)h) << 16;
  return __builtin_bit_cast(float, u);
}
__device__ __forceinline__ bf16x8 frag_ld(const unsigned short* p) {
  u16x8 v = *(const u16x8*)p;
  return __builtin_bit_cast(bf16x8, v);
}
__device__ __forceinline__ f32x4 mfma16(bf16x8 a, bf16x8 b, f32x4 c) {
  return __builtin_amdgcn_mfma_f32_16x16x32_bf16(a, b, c, 0, 0, 0);
}
__device__ __forceinline__ void async_cp16(const void* g, void* l) {
  __builtin_amdgcn_global_load_lds(
      (const __attribute__((address_space(1))) void*)g,
      (__attribute__((address_space(3))) void*)l, 16, 0, 0);
}

// ---------------------------------------------------------------------------
// elementwise fp32 -> bf16 convert (float4 per thread)
__global__ __launch_bounds__(256) void convert_bf16(const float* __restrict__ in,
                                                    unsigned short* __restrict__ out,
                                                    int n4) {
  int idx = blockIdx.x * 256 + threadIdx.x;
  if (idx < n4) {
    float4 v = ((const float4*)in)[idx];
    ushort4 o;
    o.x = f2bf(v.x); o.y = f2bf(v.y); o.z = f2bf(v.z); o.w = f2bf(v.w);
    ((ushort4*)out)[idx] = o;
  }
}

// transpose + convert: in (K x N fp32 row-major) -> out (N x K bf16, ld=ldo)
__global__ __launch_bounds__(256) void transpose_f32_bf16_ld(const float* __restrict__ in,
                                                             unsigned short* __restrict__ out,
                                                             int K, int N, int ldo) {
  __shared__ float tile[64][65];
  int n0 = blockIdx.x * 64, k0 = blockIdx.y * 64;
  int c = threadIdx.x & 63, w = threadIdx.x >> 6;
#pragma unroll
  for (int i = 0; i < 16; i++) {
    int r = w * 16 + i;
    tile[r][c] = in[(size_t)(k0 + r) * N + n0 + c];
  }
  __syncthreads();
#pragma unroll
  for (int i = 0; i < 16; i++) {
    int rr = w * 16 + i;
    out[(size_t)(n0 + rr) * ldo + k0 + c] = f2bf(tile[c][rr]);
  }
}

// v0 (B*NH slabs of [T][D] fp32) -> v0t bf16 [B*NH][D][T]
__global__ __launch_bounds__(256) void transpose_v0(const float* __restrict__ v0,
                                                    unsigned short* __restrict__ v0t) {
  __shared__ float tile[64][65];
  int s0 = blockIdx.x * 64;
  int bh = blockIdx.y;
  const float* src = v0 + (size_t)bh * T_ * HD_;
  unsigned short* dst = v0t + (size_t)bh * HD_ * T_;
  int c = threadIdx.x & 63, w = threadIdx.x >> 6;
#pragma unroll
  for (int i = 0; i < 16; i++) {
    int r = w * 16 + i;
    tile[r][c] = src[(size_t)(s0 + r) * HD_ + c];
  }
  __syncthreads();
#pragma unroll
  for (int i = 0; i < 16; i++) {
    int rr = w * 16 + i;
    dst[(size_t)rr * T_ + s0 + c] = f2bf(tile[c][rr]);
  }
}

// ---------------------------------------------------------------------------
// bf16 MFMA GEMM: C(MxN fp32) = A(MxK) * Bt(NxK)^T
// 128x128 tile, BK=32. LDS holds tiles in MFMA FRAGMENT ORDER: 8 blocks of
// (16 rows x 32 k) per tile, block stored as 64 lanes x 16B with lane l =
// (row l&15, k (l>>4)*8) — exactly the A/B-operand lane mapping. Staging via
// global_load_lds writes lane-sequentially, so fragment reads are
// frag_ld(base + lane*8): loop-invariant address, zero bank conflicts.
__global__ __launch_bounds__(256) void gemm_bf16_bt(const unsigned short* __restrict__ A,
                                                    const unsigned short* __restrict__ Bt,
                                                    float* __restrict__ C,
                                                    int M, int N, int K) {
  __shared__ unsigned short sA[128 * 32];
  __shared__ unsigned short sB[128 * 32];
  const int tid = threadIdx.x;
  const int lane = tid & 63;
  const int wave = tid >> 6;
  const int m0 = blockIdx.x * 128;
  const int n0 = blockIdx.y * 128;
  const int la = lane & 15;
  const int lq = lane >> 4;

  f32x4 acc[4][4] = {};

  // staging: wave w stages row-blocks {w, w+4} of A and of B.
  // lane l sources (row = blk*16 + (l&15), k = (l>>4)*8)
  const unsigned short* gA0 = A + (size_t)(m0 + wave * 16 + la) * K + lq * 8;
  const unsigned short* gA1 = A + (size_t)(m0 + (wave + 4) * 16 + la) * K + lq * 8;
  const unsigned short* gB0 = Bt + (size_t)(n0 + wave * 16 + la) * K + lq * 8;
  const unsigned short* gB1 = Bt + (size_t)(n0 + (wave + 4) * 16 + la) * K + lq * 8;
  unsigned short* lA0 = &sA[wave * 512];
  unsigned short* lA1 = &sA[(wave + 4) * 512];
  unsigned short* lB0 = &sB[wave * 512];
  unsigned short* lB1 = &sB[(wave + 4) * 512];

  // fragment read bases (loop-invariant, conflict-free sequential)
  const unsigned short* rA = &sA[((wave >> 1) * 4) * 512 + lane * 8];
  const unsigned short* rB = &sB[((wave & 1) * 4) * 512 + lane * 8];

  for (int k0 = 0; k0 < K; k0 += 32) {
    __syncthreads();
    async_cp16(gA0 + k0, lA0);
    async_cp16(gA1 + k0, lA1);
    async_cp16(gB0 + k0, lB0);
    async_cp16(gB1 + k0, lB1);
    __syncthreads();
    bf16x8 af[4], bfr[4];
#pragma unroll
    for (int i = 0; i < 4; i++) af[i] = frag_ld(rA + i * 512);
#pragma unroll
    for (int j = 0; j < 4; j++) bfr[j] = frag_ld(rB + j * 512);
#pragma unroll
    for (int i = 0; i < 4; i++)
#pragma unroll
      for (int j = 0; j < 4; j++) acc[i][j] = mfma16(af[i], bfr[j], acc[i][j]);
  }

  const int wm = (wave >> 1) * 64;
  const int wn = (wave & 1) * 64;
#pragma unroll
  for (int i = 0; i < 4; i++) {
    int row = m0 + wm + i * 16 + lq * 4;
#pragma unroll
    for (int j = 0; j < 4; j++) {
      int col = n0 + wn + j * 16 + la;
#pragma unroll
      for (int r = 0; r < 4; r++) C[(size_t)(row + r) * N + col] = acc[i][j][r];
    }
  }
}

// ---------------------------------------------------------------------------
// RoPE: read QKV fp32, write q_b (bf16 * CSC_, [B][NH][T][D]) and knew (fp32)
__global__ __launch_bounds__(256) void rope_kernel(const float* __restrict__ QKV,
                                                   const int* __restrict__ pos_ids,
                                                   unsigned short* __restrict__ q_b,
                                                   float* __restrict__ knew) {
  int idx = blockIdx.x * 256 + threadIdx.x;
  const int total = B_ * T_ * (NH_ + NKV_) * 32;
  if (idx >= total) return;
  int i = idx & 31;
  int tmp = idx >> 5;
  int hh = tmp % (NH_ + NKV_);
  int bt = tmp / (NH_ + NKV_);
  int t = bt & (T_ - 1);
  int b = bt >> 11;
  int pos = pos_ids[bt] + STEPS_;
  float inv = exp2f(-(float)i * (13.287712379549449f / 32.0f));
  float ang = (float)pos * inv;
  float sn, cs;
  sincosf(ang, &sn, &cs);
  const float* rowp = QKV + (size_t)bt * 3072;
  if (hh < NH_) {
    float x1 = rowp[hh * 64 + i];
    float x2 = rowp[hh * 64 + 32 + i];
    float y1 = (x1 * cs - x2 * sn) * CSC_;   // fold score scale into q
    float y2 = (x2 * cs + x1 * sn) * CSC_;
    size_t o = ((size_t)(b * NH_ + hh) * T_ + t) * HD_ + i;
    q_b[o] = f2bf(y1);
    q_b[o + 32] = f2bf(y2);
  } else {
    int kv = hh - NH_;
    float x1 = rowp[2048 + kv * 64 + i];
    float x2 = rowp[2048 + kv * 64 + 32 + i];
    float y1 = x1 * cs - x2 * sn;
    float y2 = x2 * cs + x1 * sn;
    size_t o = ((size_t)(b * NKV_ + kv) * T_ + t) * HD_ + i;
    knew[o] = y1;
    knew[o + 32] = y2;
  }
}

// ---------------------------------------------------------------------------
// Flash attention v2: 128 Q rows/block, 64-key tiles, double-buffered K/V via
// global_load_lds (XOR-swizzled through source-address permutation), ONE
// barrier per tile. Scores in exp2 domain (scale pre-folded into q).
__global__ __launch_bounds__(256, 3) void flash_kernel(const unsigned short* __restrict__ qb,
                                                       const unsigned short* __restrict__ k0b,
                                                       const unsigned short* __restrict__ v0t,
                                                       float* __restrict__ Of,
                                                       float* __restrict__ ml) {
  __shared__ unsigned short sK[2][64 * 64];
  __shared__ unsigned short sV[2][64 * 64];
  __shared__ unsigned short sP[4][16 * 72];

  const int tid = threadIdx.x;
  const int lane = tid & 63;
  const int wave = tid >> 6;
  const int la = lane & 15;
  const int lq = lane >> 4;
  const int swz = la & 7;

  const int id = blockIdx.x;
  const int bh = (id & 7) * 8 + ((id >> 3) & 7);
  const int qt = 15 - (id >> 6);

  const size_t bhs = (size_t)bh;
  const unsigned short* gK = k0b + bhs * T_ * HD_;
  const unsigned short* gV = v0t + bhs * HD_ * T_;

  const int rb0 = qt * 128 + wave * 32;
  const int ktd = rb0 >> 6;
  const int ktmax = 2 * qt + 1;

  bf16x8 aq[2][2];
#pragma unroll
  for (int f = 0; f < 2; f++) {
    const unsigned short* qp = qb + (bhs * T_ + rb0 + f * 16 + la) * HD_;
    aq[f][0] = frag_ld(qp + lq * 8);
    aq[f][1] = frag_ld(qp + 32 + lq * 8);
  }

  f32x4 o[2][4] = {};
  float m_r[2][4], l_r[2][4];
#pragma unroll
  for (int f = 0; f < 2; f++)
#pragma unroll
    for (int r = 0; r < 4; r++) { m_r[f][r] = -1e30f; l_r[f][r] = 0.0f; }

  const int lrow = lane >> 3;
  const int lcb = (lane & 7) ^ lrow;

  {
    unsigned short* kd = &sK[0][wave * 1024];
    unsigned short* vd = &sV[0][wave * 1024];
    async_cp16(gK + (size_t)(wave * 16 + lrow) * HD_ + lcb * 8, kd);
    async_cp16(gK + (size_t)(wave * 16 + 8 + lrow) * HD_ + lcb * 8, kd + 512);
    async_cp16(gV + (size_t)(wave * 16 + lrow) * T_ + lcb * 8, vd);
    async_cp16(gV + (size_t)(wave * 16 + 8 + lrow) * T_ + lcb * 8, vd + 512);
  }
  __syncthreads();

  int cur = 0;
  for (int kt = 0; kt <= ktmax; ++kt) {
    if (kt < ktmax) {
      const int nk = (kt + 1) * 64;
      unsigned short* kd = &sK[cur ^ 1][wave * 1024];
      unsigned short* vd = &sV[cur ^ 1][wave * 1024];
      async_cp16(gK + (size_t)(nk + wave * 16 + lrow) * HD_ + lcb * 8, kd);
      async_cp16(gK + (size_t)(nk + wave * 16 + 8 + lrow) * HD_ + lcb * 8, kd + 512);
      async_cp16(gV + (size_t)(wave * 16 + lrow) * T_ + nk + lcb * 8, vd);
      async_cp16(gV + (size_t)(wave * 16 + 8 + lrow) * T_ + nk + lcb * 8, vd + 512);
    }

    if (kt <= ktd) {
      const unsigned short* kb = &sK[cur][0];
      const unsigned short* vb = &sV[cur][0];

      bf16x8 bk0[4], bk1[4];
#pragma unroll
      for (int nb = 0; nb < 4; nb++) {
        const unsigned short* rp = kb + (nb * 16 + la) * 64;
        bk0[nb] = frag_ld(rp + ((lq ^ swz) << 3));
        bk1[nb] = frag_ld(rp + (((lq + 4) ^ swz) << 3));
      }
      f32x4 s[2][4];
#pragma unroll
      for (int f = 0; f < 2; f++)
#pragma unroll
        for (int nb = 0; nb < 4; nb++) {
          f32x4 z = {0.f, 0.f, 0.f, 0.f};
          z = mfma16(aq[f][0], bk0[nb], z);
          z = mfma16(aq[f][1], bk1[nb], z);
          s[f][nb] = z;
        }

      const bool diag = (kt == ktd);
#pragma unroll
      for (int f = 0; f < 2; f++) {
        if (diag) {
#pragma unroll
          for (int nb = 0; nb < 4; nb++) {
            int key = kt * 64 + nb * 16 + la;
#pragma unroll
            for (int r = 0; r < 4; r++) {
              int row = rb0 + f * 16 + lq * 4 + r;
              s[f][nb][r] = (key <= row) ? s[f][nb][r] : -1e30f;
            }
          }
        }
        float tmax[4];
#pragma unroll
        for (int r = 0; r < 4; r++)
          tmax[r] = fmaxf(fmaxf(s[f][0][r], s[f][1][r]), fmaxf(s[f][2][r], s[f][3][r]));
#pragma unroll
        for (int off = 1; off < 16; off <<= 1)
#pragma unroll
          for (int r = 0; r < 4; r++) tmax[r] = fmaxf(tmax[r], __shfl_xor(tmax[r], off));
        float al[4], ls[4] = {0.f, 0.f, 0.f, 0.f};
#pragma unroll
        for (int r = 0; r < 4; r++) {
          float mn = fmaxf(m_r[f][r], tmax[r]);
          al[r] = exp2f(m_r[f][r] - mn);
          m_r[f][r] = mn;
        }
#pragma unroll
        for (int nb = 0; nb < 4; nb++)
#pragma unroll
          for (int r = 0; r < 4; r++) {
            float p = exp2f(s[f][nb][r] - m_r[f][r]);
            s[f][nb][r] = p;
            ls[r] += p;
          }
#pragma unroll
        for (int off = 1; off < 16; off <<= 1)
#pragma unroll
          for (int r = 0; r < 4; r++) ls[r] += __shfl_xor(ls[r], off);
#pragma unroll
        for (int r = 0; r < 4; r++) l_r[f][r] = l_r[f][r] * al[r] + ls[r];
#pragma unroll
        for (int jd = 0; jd < 4; jd++)
#pragma unroll
          for (int r = 0; r < 4; r++) o[f][jd][r] *= al[r];
      }

      bf16x8 bv0[4], bv1[4];
#pragma unroll
      for (int jd = 0; jd < 4; jd++) {
        const unsigned short* rp = vb + (jd * 16 + la) * 64;
        bv0[jd] = frag_ld(rp + ((lq ^ swz) << 3));
        bv1[jd] = frag_ld(rp + (((lq + 4) ^ swz) << 3));
      }
      unsigned short* pw = &sP[wave][0];
#pragma unroll
      for (int f = 0; f < 2; f++) {
#pragma unroll
        for (int nb = 0; nb < 4; nb++)
#pragma unroll
          for (int r = 0; r < 4; r++)
            pw[(lq * 4 + r) * 72 + nb * 16 + la] = f2bf(s[f][nb][r]);
        bf16x8 ap0 = frag_ld(&pw[la * 72 + lq * 8]);
        bf16x8 ap1 = frag_ld(&pw[la * 72 + 32 + lq * 8]);
#pragma unroll
        for (int jd = 0; jd < 4; jd++) {
          o[f][jd] = mfma16(ap0, bv0[jd], o[f][jd]);
          o[f][jd] = mfma16(ap1, bv1[jd], o[f][jd]);
        }
      }
    }
    __syncthreads();
    cur ^= 1;
  }

#pragma unroll
  for (int f = 0; f < 2; f++)
#pragma unroll
    for (int jd = 0; jd < 4; jd++)
#pragma unroll
      for (int r = 0; r < 4; r++) {
        int row = rb0 + f * 16 + lq * 4 + r;
        Of[(bhs * T_ + row) * HD_ + jd * 16 + la] = o[f][jd][r];
      }
  if (la == 0) {
#pragma unroll
    for (int f = 0; f < 2; f++)
#pragma unroll
      for (int r = 0; r < 4; r++) {
        int row = rb0 + f * 16 + lq * 4 + r;
        ml[(bhs * T_ + row) * 2] = m_r[f][r];
        ml[(bhs * T_ + row) * 2 + 1] = l_r[f][r];
      }
  }
}

// ---------------------------------------------------------------------------
// Epilogue: fold the two diagonal keys (prev_k[1], new k) into the flash result.
__global__ __launch_bounds__(256) void attn_epilogue(const unsigned short* __restrict__ qb,
                                                     const float* __restrict__ prev_k,
                                                     const float* __restrict__ prev_v,
                                                     const float* __restrict__ knew,
                                                     const float* __restrict__ QKV,
                                                     const float* __restrict__ Of,
                                                     const float* __restrict__ ml,
                                                     unsigned short* __restrict__ attnout) {
  const int lane = threadIdx.x & 63;
  const int wave = threadIdx.x >> 6;
  const int row = blockIdx.x * 4 + wave;  // (b*NH+h)*T + t
  const int b = row >> 16;
  const int h = (row >> 11) & 31;
  const int t = row & 2047;
  const int d = lane;
  const size_t base = (size_t)row * HD_ + d;

  float q = bf2f(qb[base]);   // includes CSC_ factor
  const size_t p1i = ((size_t)B_ * NH_ * T_ * HD_) + (((size_t)b * NH_ + h) * T_ + t) * HD_ + d;
  float k1 = prev_k[p1i];
  float v1 = prev_v[p1i];
  int kv = h >> 2;
  float kn = knew[(((size_t)b * NKV_ + kv) * T_ + t) * HD_ + d];
  float vn = QKV[((size_t)(b * T_ + t)) * 3072 + 2560 + kv * 64 + d];

  float e1 = q * k1, e2 = q * kn;
#pragma unroll
  for (int off = 1; off < 64; off <<= 1) {
    e1 += __shfl_xor(e1, off);
    e2 += __shfl_xor(e2, off);
  }

  float m = ml[(size_t)row * 2];
  float l = ml[(size_t)row * 2 + 1];
  float mf = fmaxf(m, fmaxf(e1, e2));
  float w0 = exp2f(m - mf), w1 = exp2f(e1 - mf), w2 = exp2f(e2 - mf);
  float denom = l * w0 + w1 + w2;
  float out = (Of[base] * w0 + v1 * w1 + vn * w2) / denom;

  attnout[((size_t)(b * T_ + t)) * (NH_ * HD_) + h * HD_ + d] = f2bf(out);
}

// ---------------------------------------------------------------------------
// Workspace layout (bytes; needs ws_size >= 178,257,920)
#define OFF_QKV   ((size_t)0)
#define OFF_XB    ((size_t)50331648)
#define OFF_WQKVT ((size_t)83886080)
#define OFF_WOT   ((size_t)109051904)
#define OFF_QB    ((size_t)117440512)
#define OFF_K0B   ((size_t)134217728)
#define OFF_V0T   ((size_t)150994944)
#define OFF_KNEW  ((size_t)167772160)
#define OFF_ML    ((size_t)176160768)

extern "C" void kernel_launch(void* const* d_in, const int* in_sizes, int n_in,
                              void* d_out, int out_size, void* d_ws, size_t ws_size,
                              hipStream_t stream) {
  const float* X = (const float*)d_in[0];
  const int* pos = (const int*)d_in[2];
  const float* prevk = (const float*)d_in[3];
  const float* prevv = (const float*)d_in[4];
  const float* Wq = (const float*)d_in[5];
  const float* Wk = (const float*)d_in[6];
  const float* Wv = (const float*)d_in[7];
  const float* Wo = (const float*)d_in[8];

  char* ws = (char*)d_ws;
  float* QKV = (float*)(ws + OFF_QKV);
  unsigned short* Xb = (unsigned short*)(ws + OFF_XB);
  float* Of = (float*)(ws + OFF_XB);
  unsigned short* WqkvT = (unsigned short*)(ws + OFF_WQKVT);
  unsigned short* attnout = (unsigned short*)(ws + OFF_WQKVT);
  unsigned short* WoT = (unsigned short*)(ws + OFF_WOT);
  unsigned short* q_b = (unsigned short*)(ws + OFF_QB);
  unsigned short* k0b = (unsigned short*)(ws + OFF_K0B);
  unsigned short* v0t = (unsigned short*)(ws + OFF_V0T);
  float* knew = (float*)(ws + OFF_KNEW);
  float* ml = (float*)(ws + OFF_ML);

  convert_bf16<<<16384, 256, 0, stream>>>(X, Xb, 4194304);
  transpose_f32_bf16_ld<<<dim3(32, 64), 256, 0, stream>>>(Wq, WqkvT, 4096, 2048, 4096);
  transpose_f32_bf16_ld<<<dim3(8, 64), 256, 0, stream>>>(Wk, WqkvT + (size_t)2048 * 4096, 4096, 512, 4096);
  transpose_f32_bf16_ld<<<dim3(8, 64), 256, 0, stream>>>(Wv, WqkvT + (size_t)2560 * 4096, 4096, 512, 4096);
  transpose_f32_bf16_ld<<<dim3(32, 32), 256, 0, stream>>>(Wo, WoT, 2048, 2048, 2048);
  convert_bf16<<<8192, 256, 0, stream>>>(prevk, k0b, 2097152);
  transpose_v0<<<dim3(32, 64), 256, 0, stream>>>(prevv, v0t);

  gemm_bf16_bt<<<dim3(32, 24), 256, 0, stream>>>(Xb, WqkvT, QKV, 4096, 3072, 4096);

  rope_kernel<<<20480, 256, 0, stream>>>(QKV, pos, q_b, knew);

  flash_kernel<<<1024, 256, 0, stream>>>(q_b, k0b, v0t, Of, ml);

  attn_epilogue<<<32768, 256, 0, stream>>>(q_b, prevk, prevv, knew, QKV, Of, ml, attnout);

  gemm_bf16_bt<<<dim3(32, 16), 256, 0, stream>>>(attnout, WoT, (float*)d_out, 4096, 2048, 2048);
}

// Round 4
// 634.154 us; speedup vs baseline: 1.0734x; 1.0734x over previous
//
#include <hip/hip_runtime.h>

// Problem constants
#define B_    2
#define T_    2048
#define HID_  2048
#define NH_   32
#define NKV_  8
#define HD_   64
#define STEPS_ 2
#define SCALE_ 0.125f
// SCALE * log2(e): scores kept in exp2 domain throughout (folded into q at RoPE)
#define CSC_  0.18033688011112042f

typedef float   f32x4  __attribute__((ext_vector_type(4)));
typedef __bf16  bf16x8 __attribute__((ext_vector_type(8)));
typedef unsigned short u16x8 __attribute__((ext_vector_type(8)));

__device__ __forceinline__ unsigned short f2bf(float f) {
  unsigned int u = __builtin_bit_cast(unsigned int, f);
  u = (u + 0x7fffu + ((u >> 16) & 1u)) >> 16;
  return (unsigned short)u;
}
__device__ __forceinline__ float bf2f(unsigned short h) {
  unsigned int u = ((unsigned int)h) << 16;
  return __builtin_bit_cast(float, u);
}
__device__ __forceinline__ bf16x8 frag_ld(const unsigned short* p) {
  u16x8 v = *(const u16x8*)p;
  return __builtin_bit_cast(bf16x8, v);
}
__device__ __forceinline__ f32x4 mfma16(bf16x8 a, bf16x8 b, f32x4 c) {
  return __builtin_amdgcn_mfma_f32_16x16x32_bf16(a, b, c, 0, 0, 0);
}
__device__ __forceinline__ void async_cp16(const void* g, void* l) {
  __builtin_amdgcn_global_load_lds(
      (const __attribute__((address_space(1))) void*)g,
      (__attribute__((address_space(3))) void*)l, 16, 0, 0);
}

// ---------------------------------------------------------------------------
// elementwise fp32 -> bf16 convert (float4 per thread)
__global__ __launch_bounds__(256) void convert_bf16(const float* __restrict__ in,
                                                    unsigned short* __restrict__ out,
                                                    int n4) {
  int idx = blockIdx.x * 256 + threadIdx.x;
  if (idx < n4) {
    float4 v = ((const float4*)in)[idx];
    ushort4 o;
    o.x = f2bf(v.x); o.y = f2bf(v.y); o.z = f2bf(v.z); o.w = f2bf(v.w);
    ((ushort4*)out)[idx] = o;
  }
}

// transpose + convert: in (K x N fp32 row-major) -> out (N x K bf16, ld=ldo)
__global__ __launch_bounds__(256) void transpose_f32_bf16_ld(const float* __restrict__ in,
                                                             unsigned short* __restrict__ out,
                                                             int K, int N, int ldo) {
  __shared__ float tile[64][65];
  int n0 = blockIdx.x * 64, k0 = blockIdx.y * 64;
  int c = threadIdx.x & 63, w = threadIdx.x >> 6;
#pragma unroll
  for (int i = 0; i < 16; i++) {
    int r = w * 16 + i;
    tile[r][c] = in[(size_t)(k0 + r) * N + n0 + c];
  }
  __syncthreads();
#pragma unroll
  for (int i = 0; i < 16; i++) {
    int rr = w * 16 + i;
    out[(size_t)(n0 + rr) * ldo + k0 + c] = f2bf(tile[c][rr]);
  }
}

// v0 (B*NH slabs of [T][D] fp32) -> v0t bf16 [B*NH][D][T]
__global__ __launch_bounds__(256) void transpose_v0(const float* __restrict__ v0,
                                                    unsigned short* __restrict__ v0t) {
  __shared__ float tile[64][65];
  int s0 = blockIdx.x * 64;
  int bh = blockIdx.y;
  const float* src = v0 + (size_t)bh * T_ * HD_;
  unsigned short* dst = v0t + (size_t)bh * HD_ * T_;
  int c = threadIdx.x & 63, w = threadIdx.x >> 6;
#pragma unroll
  for (int i = 0; i < 16; i++) {
    int r = w * 16 + i;
    tile[r][c] = src[(size_t)(s0 + r) * HD_ + c];
  }
  __syncthreads();
#pragma unroll
  for (int i = 0; i < 16; i++) {
    int rr = w * 16 + i;
    dst[(size_t)rr * T_ + s0 + c] = f2bf(tile[c][rr]);
  }
}

// ---------------------------------------------------------------------------
// bf16 MFMA GEMM: C(MxN fp32) = A(MxK) * Bt(NxK)^T
// 128x128 tile, BK=32. Staging keeps R2's coalescing (4-lane groups cover one
// 64B row-run) but XOR-permutes WHICH 16B chunk each lane fetches:
//   chunk = (l&3) ^ sigma(row), sigma(r) = (r>>1)&3
// so the LDS image has fragment-read addresses
//   unit = row*4 + (lq ^ sigma(row))
// which distribute every 8-lane group over 8 distinct 16B bank-units
// (2 lanes/bank over the wave = conflict-free per m136), while the DMA still
// sees contiguous 64B runs per 4-lane group (the flash kernel's staging
// already uses within-run permutation successfully).
__global__ __launch_bounds__(256) void gemm_bf16_bt(const unsigned short* __restrict__ A,
                                                    const unsigned short* __restrict__ Bt,
                                                    float* __restrict__ C,
                                                    int M, int N, int K) {
  __shared__ unsigned short sA[128 * 32];
  __shared__ unsigned short sB[128 * 32];
  const int tid = threadIdx.x;
  const int lane = tid & 63;
  const int wave = tid >> 6;
  const int m0 = blockIdx.x * 128;
  const int n0 = blockIdx.y * 128;
  const int la = lane & 15;
  const int lq = lane >> 4;

  f32x4 acc[4][4] = {};

  // staging: lane l of each wave covers (row-in-block a = l>>2, chunk (l&3)^sigma(a))
  const int rowc = tid >> 2;                    // 0..63 global row in 64-row group
  const int sig_w = ((tid >> 3) & 3);           // sigma(a) = ((l>>2)>>1)&3 = (tid>>3)&3
  const int kc = ((tid & 3) ^ sig_w) * 8;       // swizzled k chunk (elements)
  const unsigned short* gA0 = A + (size_t)(m0 + rowc) * K + kc;
  const unsigned short* gA1 = A + (size_t)(m0 + 64 + rowc) * K + kc;
  const unsigned short* gB0 = Bt + (size_t)(n0 + rowc) * K + kc;
  const unsigned short* gB1 = Bt + (size_t)(n0 + 64 + rowc) * K + kc;
  unsigned short* lA0 = &sA[wave * 512];
  unsigned short* lA1 = &sA[2048 + wave * 512];
  unsigned short* lB0 = &sB[wave * 512];
  unsigned short* lB1 = &sB[2048 + wave * 512];

  // fragment read base: block rb holds rows rb*16..+16; within a block,
  // (row la, chunk lq) lives at unit la*4 + (lq ^ sigma(la))
  const int sig_r = (la >> 1) & 3;
  const int uoff = (la * 4 + (lq ^ sig_r)) * 8;     // element offset in 512-elem block
  const unsigned short* rA = &sA[((wave >> 1) * 4) * 512 + uoff];
  const unsigned short* rB = &sB[((wave & 1) * 4) * 512 + uoff];

  for (int k0 = 0; k0 < K; k0 += 32) {
    __syncthreads();
    async_cp16(gA0 + k0, lA0);
    async_cp16(gA1 + k0, lA1);
    async_cp16(gB0 + k0, lB0);
    async_cp16(gB1 + k0, lB1);
    __syncthreads();
    bf16x8 af[4], bfr[4];
#pragma unroll
    for (int i = 0; i < 4; i++) af[i] = frag_ld(rA + i * 512);
#pragma unroll
    for (int j = 0; j < 4; j++) bfr[j] = frag_ld(rB + j * 512);
#pragma unroll
    for (int i = 0; i < 4; i++)
#pragma unroll
      for (int j = 0; j < 4; j++) acc[i][j] = mfma16(af[i], bfr[j], acc[i][j]);
  }

  const int wm = (wave >> 1) * 64;
  const int wn = (wave & 1) * 64;
#pragma unroll
  for (int i = 0; i < 4; i++) {
    int row = m0 + wm + i * 16 + lq * 4;
#pragma unroll
    for (int j = 0; j < 4; j++) {
      int col = n0 + wn + j * 16 + la;
#pragma unroll
      for (int r = 0; r < 4; r++) C[(size_t)(row + r) * N + col] = acc[i][j][r];
    }
  }
}

// ---------------------------------------------------------------------------
// RoPE: read QKV fp32, write q_b (bf16 * CSC_, [B][NH][T][D]) and knew (fp32)
__global__ __launch_bounds__(256) void rope_kernel(const float* __restrict__ QKV,
                                                   const int* __restrict__ pos_ids,
                                                   unsigned short* __restrict__ q_b,
                                                   float* __restrict__ knew) {
  int idx = blockIdx.x * 256 + threadIdx.x;
  const int total = B_ * T_ * (NH_ + NKV_) * 32;
  if (idx >= total) return;
  int i = idx & 31;
  int tmp = idx >> 5;
  int hh = tmp % (NH_ + NKV_);
  int bt = tmp / (NH_ + NKV_);
  int t = bt & (T_ - 1);
  int b = bt >> 11;
  int pos = pos_ids[bt] + STEPS_;
  float inv = exp2f(-(float)i * (13.287712379549449f / 32.0f));
  float ang = (float)pos * inv;
  float sn, cs;
  sincosf(ang, &sn, &cs);
  const float* rowp = QKV + (size_t)bt * 3072;
  if (hh < NH_) {
    float x1 = rowp[hh * 64 + i];
    float x2 = rowp[hh * 64 + 32 + i];
    float y1 = (x1 * cs - x2 * sn) * CSC_;   // fold score scale into q
    float y2 = (x2 * cs + x1 * sn) * CSC_;
    size_t o = ((size_t)(b * NH_ + hh) * T_ + t) * HD_ + i;
    q_b[o] = f2bf(y1);
    q_b[o + 32] = f2bf(y2);
  } else {
    int kv = hh - NH_;
    float x1 = rowp[2048 + kv * 64 + i];
    float x2 = rowp[2048 + kv * 64 + 32 + i];
    float y1 = x1 * cs - x2 * sn;
    float y2 = x2 * cs + x1 * sn;
    size_t o = ((size_t)(b * NKV_ + kv) * T_ + t) * HD_ + i;
    knew[o] = y1;
    knew[o + 32] = y2;
  }
}

// ---------------------------------------------------------------------------
// Flash attention v2: 128 Q rows/block, 64-key tiles, double-buffered K/V via
// global_load_lds (XOR-swizzled through source-address permutation), ONE
// barrier per tile. Scores in exp2 domain (scale pre-folded into q).
__global__ __launch_bounds__(256, 3) void flash_kernel(const unsigned short* __restrict__ qb,
                                                       const unsigned short* __restrict__ k0b,
                                                       const unsigned short* __restrict__ v0t,
                                                       float* __restrict__ Of,
                                                       float* __restrict__ ml) {
  __shared__ unsigned short sK[2][64 * 64];
  __shared__ unsigned short sV[2][64 * 64];
  __shared__ unsigned short sP[4][16 * 72];

  const int tid = threadIdx.x;
  const int lane = tid & 63;
  const int wave = tid >> 6;
  const int la = lane & 15;
  const int lq = lane >> 4;
  const int swz = la & 7;

  const int id = blockIdx.x;
  const int bh = (id & 7) * 8 + ((id >> 3) & 7);
  const int qt = 15 - (id >> 6);

  const size_t bhs = (size_t)bh;
  const unsigned short* gK = k0b + bhs * T_ * HD_;
  const unsigned short* gV = v0t + bhs * HD_ * T_;

  const int rb0 = qt * 128 + wave * 32;
  const int ktd = rb0 >> 6;
  const int ktmax = 2 * qt + 1;

  bf16x8 aq[2][2];
#pragma unroll
  for (int f = 0; f < 2; f++) {
    const unsigned short* qp = qb + (bhs * T_ + rb0 + f * 16 + la) * HD_;
    aq[f][0] = frag_ld(qp + lq * 8);
    aq[f][1] = frag_ld(qp + 32 + lq * 8);
  }

  f32x4 o[2][4] = {};
  float m_r[2][4], l_r[2][4];
#pragma unroll
  for (int f = 0; f < 2; f++)
#pragma unroll
    for (int r = 0; r < 4; r++) { m_r[f][r] = -1e30f; l_r[f][r] = 0.0f; }

  const int lrow = lane >> 3;
  const int lcb = (lane & 7) ^ lrow;

  {
    unsigned short* kd = &sK[0][wave * 1024];
    unsigned short* vd = &sV[0][wave * 1024];
    async_cp16(gK + (size_t)(wave * 16 + lrow) * HD_ + lcb * 8, kd);
    async_cp16(gK + (size_t)(wave * 16 + 8 + lrow) * HD_ + lcb * 8, kd + 512);
    async_cp16(gV + (size_t)(wave * 16 + lrow) * T_ + lcb * 8, vd);
    async_cp16(gV + (size_t)(wave * 16 + 8 + lrow) * T_ + lcb * 8, vd + 512);
  }
  __syncthreads();

  int cur = 0;
  for (int kt = 0; kt <= ktmax; ++kt) {
    if (kt < ktmax) {
      const int nk = (kt + 1) * 64;
      unsigned short* kd = &sK[cur ^ 1][wave * 1024];
      unsigned short* vd = &sV[cur ^ 1][wave * 1024];
      async_cp16(gK + (size_t)(nk + wave * 16 + lrow) * HD_ + lcb * 8, kd);
      async_cp16(gK + (size_t)(nk + wave * 16 + 8 + lrow) * HD_ + lcb * 8, kd + 512);
      async_cp16(gV + (size_t)(wave * 16 + lrow) * T_ + nk + lcb * 8, vd);
      async_cp16(gV + (size_t)(wave * 16 + 8 + lrow) * T_ + nk + lcb * 8, vd + 512);
    }

    if (kt <= ktd) {
      const unsigned short* kb = &sK[cur][0];
      const unsigned short* vb = &sV[cur][0];

      bf16x8 bk0[4], bk1[4];
#pragma unroll
      for (int nb = 0; nb < 4; nb++) {
        const unsigned short* rp = kb + (nb * 16 + la) * 64;
        bk0[nb] = frag_ld(rp + ((lq ^ swz) << 3));
        bk1[nb] = frag_ld(rp + (((lq + 4) ^ swz) << 3));
      }
      f32x4 s[2][4];
#pragma unroll
      for (int f = 0; f < 2; f++)
#pragma unroll
        for (int nb = 0; nb < 4; nb++) {
          f32x4 z = {0.f, 0.f, 0.f, 0.f};
          z = mfma16(aq[f][0], bk0[nb], z);
          z = mfma16(aq[f][1], bk1[nb], z);
          s[f][nb] = z;
        }

      const bool diag = (kt == ktd);
#pragma unroll
      for (int f = 0; f < 2; f++) {
        if (diag) {
#pragma unroll
          for (int nb = 0; nb < 4; nb++) {
            int key = kt * 64 + nb * 16 + la;
#pragma unroll
            for (int r = 0; r < 4; r++) {
              int row = rb0 + f * 16 + lq * 4 + r;
              s[f][nb][r] = (key <= row) ? s[f][nb][r] : -1e30f;
            }
          }
        }
        float tmax[4];
#pragma unroll
        for (int r = 0; r < 4; r++)
          tmax[r] = fmaxf(fmaxf(s[f][0][r], s[f][1][r]), fmaxf(s[f][2][r], s[f][3][r]));
#pragma unroll
        for (int off = 1; off < 16; off <<= 1)
#pragma unroll
          for (int r = 0; r < 4; r++) tmax[r] = fmaxf(tmax[r], __shfl_xor(tmax[r], off));
        float al[4], ls[4] = {0.f, 0.f, 0.f, 0.f};
#pragma unroll
        for (int r = 0; r < 4; r++) {
          float mn = fmaxf(m_r[f][r], tmax[r]);
          al[r] = exp2f(m_r[f][r] - mn);
          m_r[f][r] = mn;
        }
#pragma unroll
        for (int nb = 0; nb < 4; nb++)
#pragma unroll
          for (int r = 0; r < 4; r++) {
            float p = exp2f(s[f][nb][r] - m_r[f][r]);
            s[f][nb][r] = p;
            ls[r] += p;
          }
#pragma unroll
        for (int off = 1; off < 16; off <<= 1)
#pragma unroll
          for (int r = 0; r < 4; r++) ls[r] += __shfl_xor(ls[r], off);
#pragma unroll
        for (int r = 0; r < 4; r++) l_r[f][r] = l_r[f][r] * al[r] + ls[r];
#pragma unroll
        for (int jd = 0; jd < 4; jd++)
#pragma unroll
          for (int r = 0; r < 4; r++) o[f][jd][r] *= al[r];
      }

      bf16x8 bv0[4], bv1[4];
#pragma unroll
      for (int jd = 0; jd < 4; jd++) {
        const unsigned short* rp = vb + (jd * 16 + la) * 64;
        bv0[jd] = frag_ld(rp + ((lq ^ swz) << 3));
        bv1[jd] = frag_ld(rp + (((lq + 4) ^ swz) << 3));
      }
      unsigned short* pw = &sP[wave][0];
#pragma unroll
      for (int f = 0; f < 2; f++) {
#pragma unroll
        for (int nb = 0; nb < 4; nb++)
#pragma unroll
          for (int r = 0; r < 4; r++)
            pw[(lq * 4 + r) * 72 + nb * 16 + la] = f2bf(s[f][nb][r]);
        bf16x8 ap0 = frag_ld(&pw[la * 72 + lq * 8]);
        bf16x8 ap1 = frag_ld(&pw[la * 72 + 32 + lq * 8]);
#pragma unroll
        for (int jd = 0; jd < 4; jd++) {
          o[f][jd] = mfma16(ap0, bv0[jd], o[f][jd]);
          o[f][jd] = mfma16(ap1, bv1[jd], o[f][jd]);
        }
      }
    }
    __syncthreads();
    cur ^= 1;
  }

#pragma unroll
  for (int f = 0; f < 2; f++)
#pragma unroll
    for (int jd = 0; jd < 4; jd++)
#pragma unroll
      for (int r = 0; r < 4; r++) {
        int row = rb0 + f * 16 + lq * 4 + r;
        Of[(bhs * T_ + row) * HD_ + jd * 16 + la] = o[f][jd][r];
      }
  if (la == 0) {
#pragma unroll
    for (int f = 0; f < 2; f++)
#pragma unroll
      for (int r = 0; r < 4; r++) {
        int row = rb0 + f * 16 + lq * 4 + r;
        ml[(bhs * T_ + row) * 2] = m_r[f][r];
        ml[(bhs * T_ + row) * 2 + 1] = l_r[f][r];
      }
  }
}

// ---------------------------------------------------------------------------
// Epilogue: fold the two diagonal keys (prev_k[1], new k) into the flash result.
__global__ __launch_bounds__(256) void attn_epilogue(const unsigned short* __restrict__ qb,
                                                     const float* __restrict__ prev_k,
                                                     const float* __restrict__ prev_v,
                                                     const float* __restrict__ knew,
                                                     const float* __restrict__ QKV,
                                                     const float* __restrict__ Of,
                                                     const float* __restrict__ ml,
                                                     unsigned short* __restrict__ attnout) {
  const int lane = threadIdx.x & 63;
  const int wave = threadIdx.x >> 6;
  const int row = blockIdx.x * 4 + wave;  // (b*NH+h)*T + t
  const int b = row >> 16;
  const int h = (row >> 11) & 31;
  const int t = row & 2047;
  const int d = lane;
  const size_t base = (size_t)row * HD_ + d;

  float q = bf2f(qb[base]);   // includes CSC_ factor
  const size_t p1i = ((size_t)B_ * NH_ * T_ * HD_) + (((size_t)b * NH_ + h) * T_ + t) * HD_ + d;
  float k1 = prev_k[p1i];
  float v1 = prev_v[p1i];
  int kv = h >> 2;
  float kn = knew[(((size_t)b * NKV_ + kv) * T_ + t) * HD_ + d];
  float vn = QKV[((size_t)(b * T_ + t)) * 3072 + 2560 + kv * 64 + d];

  float e1 = q * k1, e2 = q * kn;
#pragma unroll
  for (int off = 1; off < 64; off <<= 1) {
    e1 += __shfl_xor(e1, off);
    e2 += __shfl_xor(e2, off);
  }

  float m = ml[(size_t)row * 2];
  float l = ml[(size_t)row * 2 + 1];
  float mf = fmaxf(m, fmaxf(e1, e2));
  float w0 = exp2f(m - mf), w1 = exp2f(e1 - mf), w2 = exp2f(e2 - mf);
  float denom = l * w0 + w1 + w2;
  float out = (Of[base] * w0 + v1 * w1 + vn * w2) / denom;

  attnout[((size_t)(b * T_ + t)) * (NH_ * HD_) + h * HD_ + d] = f2bf(out);
}

// ---------------------------------------------------------------------------
// Workspace layout (bytes; needs ws_size >= 178,257,920)
#define OFF_QKV   ((size_t)0)
#define OFF_XB    ((size_t)50331648)
#define OFF_WQKVT ((size_t)83886080)
#define OFF_WOT   ((size_t)109051904)
#define OFF_QB    ((size_t)117440512)
#define OFF_K0B   ((size_t)134217728)
#define OFF_V0T   ((size_t)150994944)
#define OFF_KNEW  ((size_t)167772160)
#define OFF_ML    ((size_t)176160768)

extern "C" void kernel_launch(void* const* d_in, const int* in_sizes, int n_in,
                              void* d_out, int out_size, void* d_ws, size_t ws_size,
                              hipStream_t stream) {
  const float* X = (const float*)d_in[0];
  const int* pos = (const int*)d_in[2];
  const float* prevk = (const float*)d_in[3];
  const float* prevv = (const float*)d_in[4];
  const float* Wq = (const float*)d_in[5];
  const float* Wk = (const float*)d_in[6];
  const float* Wv = (const float*)d_in[7];
  const float* Wo = (const float*)d_in[8];

  char* ws = (char*)d_ws;
  float* QKV = (float*)(ws + OFF_QKV);
  unsigned short* Xb = (unsigned short*)(ws + OFF_XB);
  float* Of = (float*)(ws + OFF_XB);
  unsigned short* WqkvT = (unsigned short*)(ws + OFF_WQKVT);
  unsigned short* attnout = (unsigned short*)(ws + OFF_WQKVT);
  unsigned short* WoT = (unsigned short*)(ws + OFF_WOT);
  unsigned short* q_b = (unsigned short*)(ws + OFF_QB);
  unsigned short* k0b = (unsigned short*)(ws + OFF_K0B);
  unsigned short* v0t = (unsigned short*)(ws + OFF_V0T);
  float* knew = (float*)(ws + OFF_KNEW);
  float* ml = (float*)(ws + OFF_ML);

  convert_bf16<<<16384, 256, 0, stream>>>(X, Xb, 4194304);
  transpose_f32_bf16_ld<<<dim3(32, 64), 256, 0, stream>>>(Wq, WqkvT, 4096, 2048, 4096);
  transpose_f32_bf16_ld<<<dim3(8, 64), 256, 0, stream>>>(Wk, WqkvT + (size_t)2048 * 4096, 4096, 512, 4096);
  transpose_f32_bf16_ld<<<dim3(8, 64), 256, 0, stream>>>(Wv, WqkvT + (size_t)2560 * 4096, 4096, 512, 4096);
  transpose_f32_bf16_ld<<<dim3(32, 32), 256, 0, stream>>>(Wo, WoT, 2048, 2048, 2048);
  convert_bf16<<<8192, 256, 0, stream>>>(prevk, k0b, 2097152);
  transpose_v0<<<dim3(32, 64), 256, 0, stream>>>(prevv, v0t);

  gemm_bf16_bt<<<dim3(32, 24), 256, 0, stream>>>(Xb, WqkvT, QKV, 4096, 3072, 4096);

  rope_kernel<<<20480, 256, 0, stream>>>(QKV, pos, q_b, knew);

  flash_kernel<<<1024, 256, 0, stream>>>(q_b, k0b, v0t, Of, ml);

  attn_epilogue<<<32768, 256, 0, stream>>>(q_b, prevk, prevv, knew, QKV, Of, ml, attnout);

  gemm_bf16_bt<<<dim3(32, 16), 256, 0, stream>>>(attnout, WoT, (float*)d_out, 4096, 2048, 2048);
}